// Round 2
// baseline (631.743 us; speedup 1.0000x reference)
//
#include <hip/hip_runtime.h>
#include <hip/hip_bf16.h>

// BNTChannelAttention: qkv = x@W + b; per (b,h): attn = softmax(Q^T K / 8) over
// channel dim (64x64), out = V @ attn.  B=8 N=4096 d_hid=1024 H=16 Dh=64.
//
// Round 2: k_gemm1 upgraded to the 256x256 8-phase template (T2 st_16x32 LDS
// swizzle + T3/T4 counted vmcnt + T5 setprio). All other kernels bit-identical
// to round 1 (absmax must stay exactly 0.2119).
//
// 8-phase schedule (2 K-tiles/iter, buf0=even kt, buf1=odd kt):
//   ph0: ld A[mh0],B[nh0] buf0 | stage Bh0(kt=2i+1)->buf1 | MM(0,0)
//   ph1: ld A[mh1]        buf0 | stage Bh1(kt=2i+1)->buf1 | MM(1,0)
//   ph2: ld B[nh1]        buf0 | stage Ah0(kt=2i+2)->buf0 | MM(1,1)
//   ph3:                       | stage Ah1(kt=2i+2)->buf0 | MM(0,1) vmcnt(4)
//   ph4..7: same with buf1 frags, stage Bh0/Bh1(kt=2i+2)->buf0,
//           Ah0/Ah1(kt=2i+3)->buf1, vmcnt(4) at ph7.
// Each staged half-tile's region was last ds_read >=1 phase before its stage
// issue (barrier-separated); vmcnt(4)+barrier guarantees landing before reads.

typedef __attribute__((ext_vector_type(4))) float  f32x4;
typedef __attribute__((ext_vector_type(8))) short  bf16x8;
typedef __attribute__((ext_vector_type(8))) unsigned short u16x8;

typedef __attribute__((address_space(1))) const unsigned int GBUF;
typedef __attribute__((address_space(3))) unsigned int       LBUF;

#define DEVI __device__ __forceinline__

static constexpr int BATCH = 8;
static constexpr int NSEQ  = 4096;
static constexpr int DHID  = 1024;
static constexpr int NHEAD = 16;
static constexpr int DH    = 64;
static constexpr int MROWS = BATCH * NSEQ;   // 32768
static constexpr int N3    = 3 * DHID;       // 3072

DEVI unsigned short f2bf(float f) {
    unsigned int u = __float_as_uint(f);
    u = (u + 0x7fffu + ((u >> 16) & 1u)) >> 16;   // round-to-nearest-even
    return (unsigned short)u;
}

// ---------------------------------------------------------------- 1) x -> bf16
__global__ void k_cvt_x(const float* __restrict__ x, unsigned short* __restrict__ xb, int n8) {
    int i = blockIdx.x * 256 + threadIdx.x;
    int stride = gridDim.x * 256;
    for (; i < n8; i += stride) {
        f32x4 a = *(const f32x4*)(x + (size_t)i * 8);
        f32x4 b = *(const f32x4*)(x + (size_t)i * 8 + 4);
        u16x8 r;
#pragma unroll
        for (int j = 0; j < 4; j++) { r[j] = f2bf(a[j]); r[4 + j] = f2bf(b[j]); }
        *(u16x8*)(xb + (size_t)i * 8) = r;
    }
}

// ------------------------------------------------- 2) W [1024][3072] -> Wt bf16
__global__ void k_wt(const float* __restrict__ W, unsigned short* __restrict__ Wt) {
    __shared__ float s[32][33];
    int c0 = blockIdx.x * 32;      // col in N3
    int k0 = blockIdx.y * 32;      // row in K
    int tx = threadIdx.x & 31, ty = threadIdx.x >> 5;   // 32x8
#pragma unroll
    for (int i = 0; i < 4; i++)
        s[ty + 8 * i][tx] = W[(size_t)(k0 + ty + 8 * i) * N3 + c0 + tx];
    __syncthreads();
#pragma unroll
    for (int i = 0; i < 4; i++)
        Wt[(size_t)(c0 + ty + 8 * i) * DHID + k0 + tx] = f2bf(s[tx][ty + 8 * i]);
}

// ------------------------------------------------------------- 3) QKV GEMM
// 256x256 tile, BK=64, 512 thr = 8 waves (2M x 4N), 8-phase schedule.
// LDS: As/Bs [2 buf][256 rows][64 k] bf16, st_16x32 swizzle = col ^ ((row>>2&1)*16).
__global__ __launch_bounds__(512, 2) void k_gemm1(
        const unsigned short* __restrict__ xb, const unsigned short* __restrict__ Wt,
        const float* __restrict__ bias,
        unsigned short* __restrict__ Q, unsigned short* __restrict__ Kw,
        unsigned short* __restrict__ V) {
    __shared__ __align__(16) unsigned short As[2][16384];
    __shared__ __align__(16) unsigned short Bs[2][16384];

    int nwg = gridDim.x;
    int cpx = nwg >> 3;                        // 1536 % 8 == 0 -> bijective
    int id  = blockIdx.x;
    int swz = (id & 7) * cpx + (id >> 3);
    int mt = swz / 12, nt = swz % 12;
    int m0 = mt * 256, n0 = nt * 256;

    int t = threadIdx.x, l = t & 63, w = t >> 6;
    int wr = w >> 2, wc = w & 3;               // 2 x 4 wave grid
    int lr = l & 15;

    const unsigned short* aSrc = xb + (size_t)m0 * DHID;
    const unsigned short* bSrc = Wt + (size_t)n0 * DHID;

    // staging: thread t covers row (h*128 + j*64 + t>>3), cols (t&7)*8 ^ swz16
    int scol = ((t & 7) * 8) ^ (((t >> 5) & 1) << 4);
    // frag reads: row = base + lr; col = kk*32 + (l>>4)*8, swizzled per-lane
    int cSwz = (((l >> 4)) * 8) ^ (((lr >> 2) & 1) << 4);
    int aRow = wr * 128 + lr;
    int bRow = wc * 64 + lr;

#define STAGE_A(bi, kt, h) do { \
        const unsigned short* _s = aSrc + (size_t)((h) * 128 + (t >> 3)) * DHID + (kt) * 64 + scol; \
        unsigned short* _d = &As[bi][(h) * 8192 + t * 8]; \
        __builtin_amdgcn_global_load_lds((GBUF*)_s, (LBUF*)_d, 16, 0, 0); \
        __builtin_amdgcn_global_load_lds((GBUF*)(_s + 64 * DHID), (LBUF*)(_d + 4096), 16, 0, 0); \
    } while (0)
#define STAGE_B(bi, kt, h) do { \
        const unsigned short* _s = bSrc + (size_t)((h) * 128 + (t >> 3)) * DHID + (kt) * 64 + scol; \
        unsigned short* _d = &Bs[bi][(h) * 8192 + t * 8]; \
        __builtin_amdgcn_global_load_lds((GBUF*)_s, (LBUF*)_d, 16, 0, 0); \
        __builtin_amdgcn_global_load_lds((GBUF*)(_s + 64 * DHID), (LBUF*)(_d + 4096), 16, 0, 0); \
    } while (0)
#define LDA(bi, dst, mh) \
    _Pragma("unroll") for (int m2 = 0; m2 < 4; m2++) { \
        const unsigned short* _p = &As[bi][(aRow + (mh) * 64 + m2 * 16) * 64 + cSwz]; \
        dst[m2][0] = *(const bf16x8*)_p; \
        dst[m2][1] = *(const bf16x8*)(_p + 32); \
    }
#define LDB(bi, dst, nh) \
    _Pragma("unroll") for (int n2 = 0; n2 < 2; n2++) { \
        const unsigned short* _p = &Bs[bi][(bRow + (nh) * 32 + n2 * 16) * 64 + cSwz]; \
        dst[n2][0] = *(const bf16x8*)_p; \
        dst[n2][1] = *(const bf16x8*)(_p + 32); \
    }
#define MM(mh, nh, A_, B_) \
    _Pragma("unroll") for (int m2 = 0; m2 < 4; m2++) \
    _Pragma("unroll") for (int n2 = 0; n2 < 2; n2++) { \
        acc[(mh)*4+m2][(nh)*2+n2] = __builtin_amdgcn_mfma_f32_16x16x32_bf16(A_[m2][0], B_[n2][0], acc[(mh)*4+m2][(nh)*2+n2], 0, 0, 0); \
        acc[(mh)*4+m2][(nh)*2+n2] = __builtin_amdgcn_mfma_f32_16x16x32_bf16(A_[m2][1], B_[n2][1], acc[(mh)*4+m2][(nh)*2+n2], 0, 0, 0); \
    }
#define BAR __builtin_amdgcn_s_barrier()
#define LGKM0 do { asm volatile("s_waitcnt lgkmcnt(0)" ::: "memory"); \
                   __builtin_amdgcn_sched_barrier(0); } while (0)
#define VM4 asm volatile("s_waitcnt vmcnt(4)" ::: "memory")
#define PRIO1 __builtin_amdgcn_s_setprio(1)
#define PRIO0 __builtin_amdgcn_s_setprio(0)

    f32x4 acc[8][4] = {};
    bf16x8 fA0[4][2], fA1[4][2], fB0[2][2], fB1[2][2];

    // prologue: buf0 = kt0 full, buf1 = kt1 A-halves (B staged in iter0 ph0/1)
    STAGE_A(0, 0, 0); STAGE_A(0, 0, 1);
    STAGE_B(0, 0, 0); STAGE_B(0, 0, 1);
    STAGE_A(1, 1, 0); STAGE_A(1, 1, 1);
    VM4;            // oldest 8 (= all of buf0) landed
    BAR;

#pragma unroll 1
    for (int i = 0; i < 8; ++i) {
        int kc1 = 2 * i + 1;
        int kn0 = (2 * i + 2) & 15, kn1 = (2 * i + 3) & 15;  // iter7 wraps (redundant, safe)
        // ---- K-tile 2i from buf0 ----
        LDA(0, fA0, 0); LDB(0, fB0, 0); STAGE_B(1, kc1, 0);
        BAR; LGKM0; PRIO1; MM(0, 0, fA0, fB0); PRIO0; BAR;

        LDA(0, fA1, 1); STAGE_B(1, kc1, 1);
        BAR; LGKM0; PRIO1; MM(1, 0, fA1, fB0); PRIO0; BAR;

        LDB(0, fB1, 1); STAGE_A(0, kn0, 0);
        BAR; LGKM0; PRIO1; MM(1, 1, fA1, fB1); PRIO0; BAR;

        STAGE_A(0, kn0, 1);
        BAR; PRIO1; MM(0, 1, fA0, fB1); PRIO0;
        VM4;        // buf1 (A: prologue/ph6-7 prev, B: ph0-1) landed
        BAR;
        // ---- K-tile 2i+1 from buf1 ----
        LDA(1, fA0, 0); LDB(1, fB0, 0); STAGE_B(0, kn0, 0);
        BAR; LGKM0; PRIO1; MM(0, 0, fA0, fB0); PRIO0; BAR;

        LDA(1, fA1, 1); STAGE_B(0, kn0, 1);
        BAR; LGKM0; PRIO1; MM(1, 0, fA1, fB0); PRIO0; BAR;

        LDB(1, fB1, 1); STAGE_A(1, kn1, 0);
        BAR; LGKM0; PRIO1; MM(1, 1, fA1, fB1); PRIO0; BAR;

        STAGE_A(1, kn1, 1);
        BAR; PRIO1; MM(0, 1, fA0, fB1); PRIO0;
        VM4;        // buf0 next content (A: ph2-3, B: ph4-5) landed
        BAR;
    }

    // epilogue: +bias, scatter to Q/K/V [b*16+h][n][e] bf16
    int hg   = nt * 4 + wc;               // head-slot 0..47 (64 cols = 1 head)
    int part = hg >> 4;
    int h    = hg & 15;
    unsigned short* dst = (part == 0) ? Q : ((part == 1) ? Kw : V);
    int b   = m0 >> 12;                   // 256-row tile never straddles batch
    int nnb = m0 & 4095;
    unsigned short* dstp = dst + ((size_t)(b * 16 + h) * NSEQ) * DH;

#pragma unroll
    for (int n = 0; n < 4; n++) {
        int e    = n * 16 + lr;
        float bv = bias[n0 + wc * 64 + n * 16 + lr];
#pragma unroll
        for (int m = 0; m < 8; m++) {
            int r0 = nnb + wr * 128 + m * 16 + (l >> 4) * 4;
#pragma unroll
            for (int j = 0; j < 4; j++)
                dstp[(size_t)(r0 + j) * DH + e] = f2bf(acc[m][n][j] + bv);
        }
    }
#undef STAGE_A
#undef STAGE_B
#undef LDA
#undef LDB
#undef MM
#undef BAR
#undef LGKM0
#undef VM4
#undef PRIO1
#undef PRIO0
}

// ------------------------------------------- 4) logit partials  P[d][e] (fp32)
// grid = 128 bh * 4 chunks; wg = 256 thr; K-chunk = 1024 rows of N.
__global__ __launch_bounds__(256, 2) void k_qk(
        const unsigned short* __restrict__ Q, const unsigned short* __restrict__ K,
        float* __restrict__ part) {
    __shared__ unsigned short Qt[64 * 40];   // [d][n] pad to 40 shorts (80B rows)
    __shared__ unsigned short Kt[64 * 40];   // 16B-aligned rows, ~2-way banks

    int bid = blockIdx.x;
    int bh = bid >> 2, ch = bid & 3;
    const unsigned short* Qb = Q + ((size_t)bh * NSEQ + ch * 1024) * DH;
    const unsigned short* Kb = K + ((size_t)bh * NSEQ + ch * 1024) * DH;

    int t = threadIdx.x, l = t & 63, w = t >> 6;
    int wr = w >> 1, wc = w & 1;
    int nn = t & 31;          // n within 32-row tile
    int dg = t >> 5;          // d-group 0..7 (8 d's each)

    f32x4 acc[2][2] = {};

    for (int ns = 0; ns < 32; ns++) {
        const size_t ro = (size_t)(ns * 32 + nn) * DH + dg * 8;
        bf16x8 qv = *(const bf16x8*)(Qb + ro);
        bf16x8 kv = *(const bf16x8*)(Kb + ro);
        __syncthreads();                       // prior frag reads done
#pragma unroll
        for (int j = 0; j < 8; j++) {
            Qt[(dg * 8 + j) * 40 + nn] = qv[j];
            Kt[(dg * 8 + j) * 40 + nn] = kv[j];
        }
        __syncthreads();
        bf16x8 a[2], b[2];
#pragma unroll
        for (int m = 0; m < 2; m++)
            a[m] = *(const bf16x8*)(Qt + (wr * 32 + m * 16 + (l & 15)) * 40 + (l >> 4) * 8);
#pragma unroll
        for (int n = 0; n < 2; n++)
            b[n] = *(const bf16x8*)(Kt + (wc * 32 + n * 16 + (l & 15)) * 40 + (l >> 4) * 8);
#pragma unroll
        for (int m = 0; m < 2; m++)
#pragma unroll
            for (int n = 0; n < 2; n++)
                acc[m][n] = __builtin_amdgcn_mfma_f32_16x16x32_bf16(a[m], b[n], acc[m][n], 0, 0, 0);
    }

    float* P = part + ((size_t)ch * 128 + bh) * 4096;
#pragma unroll
    for (int m = 0; m < 2; m++)
#pragma unroll
        for (int n = 0; n < 2; n++)
#pragma unroll
            for (int j = 0; j < 4; j++) {
                int d = wr * 32 + m * 16 + (l >> 4) * 4 + j;
                int e = wc * 32 + n * 16 + (l & 15);
                P[d * 64 + e] = acc[m][n][j];
            }
}

// --------------------------------------- 5) softmax over e, write attn^T bf16
__global__ void k_softmax(const float* __restrict__ part, unsigned short* __restrict__ attn_t) {
    int bh = blockIdx.x;          // 128
    int d  = threadIdx.x;         // 64
    const float* p = part + (size_t)bh * 4096 + d * 64;
    const size_t cs = (size_t)128 * 4096;
    float s[64];
#pragma unroll
    for (int e = 0; e < 64; e++)
        s[e] = (p[e] + p[cs + e] + p[2 * cs + e] + p[3 * cs + e]) * 0.125f;
    float mx = s[0];
#pragma unroll
    for (int e = 1; e < 64; e++) mx = fmaxf(mx, s[e]);
    float sum = 0.f;
#pragma unroll
    for (int e = 0; e < 64; e++) { s[e] = __expf(s[e] - mx); sum += s[e]; }
    float inv = 1.f / sum;
    unsigned short* a = attn_t + (size_t)bh * 4096;
#pragma unroll
    for (int e = 0; e < 64; e++)
        a[e * 64 + d] = f2bf(s[e] * inv);     // [e][d] layout for PV B-frags
}

// ------------------------------------------------------- 6) out = V @ attn
// grid = 128 bh * 16 row-tiles; wave owns 64 rows x 64 cols; no LDS.
__global__ __launch_bounds__(256, 2) void k_out(
        const unsigned short* __restrict__ V, const unsigned short* __restrict__ attn_t,
        float* __restrict__ out) {
    int bid = blockIdx.x;
    int bh = bid >> 4, ntile = bid & 15;
    int b = bh >> 4, h = bh & 15;
    int t = threadIdx.x, l = t & 63, w = t >> 6;
    int r0 = ntile * 256 + w * 64;

    const unsigned short* Vb = V + (size_t)bh * NSEQ * DH;
    const unsigned short* Ab = attn_t + (size_t)bh * 4096;

    bf16x8 bf[4][2];
#pragma unroll
    for (int n = 0; n < 4; n++)
#pragma unroll
        for (int ks = 0; ks < 2; ks++)
            bf[n][ks] = *(const bf16x8*)(Ab + (n * 16 + (l & 15)) * 64 + ks * 32 + (l >> 4) * 8);

    f32x4 acc[4][4] = {};
#pragma unroll
    for (int m = 0; m < 4; m++) {
        const unsigned short* vr = Vb + (size_t)(r0 + m * 16 + (l & 15)) * DH + (l >> 4) * 8;
        bf16x8 av0 = *(const bf16x8*)(vr);
        bf16x8 av1 = *(const bf16x8*)(vr + 32);
#pragma unroll
        for (int n = 0; n < 4; n++) {
            acc[m][n] = __builtin_amdgcn_mfma_f32_16x16x32_bf16(av0, bf[n][0], acc[m][n], 0, 0, 0);
            acc[m][n] = __builtin_amdgcn_mfma_f32_16x16x32_bf16(av1, bf[n][1], acc[m][n], 0, 0, 0);
        }
    }

    float* ob = out + (size_t)b * NSEQ * DHID + (size_t)h * DH;
#pragma unroll
    for (int m = 0; m < 4; m++)
#pragma unroll
        for (int n = 0; n < 4; n++)
#pragma unroll
            for (int j = 0; j < 4; j++) {
                int nn = r0 + m * 16 + (l >> 4) * 4 + j;
                int e  = n * 16 + (l & 15);
                ob[(size_t)nn * DHID + e] = acc[m][n][j];
            }
}

// ---------------------------------------------------------------- launcher
extern "C" void kernel_launch(void* const* d_in, const int* in_sizes, int n_in,
                              void* d_out, int out_size, void* d_ws, size_t ws_size,
                              hipStream_t stream) {
    const float* x    = (const float*)d_in[0];
    const float* W    = (const float*)d_in[1];
    const float* bias = (const float*)d_in[2];
    float* out = (float*)d_out;

    char* wsp = (char*)d_ws;
    unsigned short* xb   = (unsigned short*)(wsp);                 //  67,108,864 B
    unsigned short* Wt   = (unsigned short*)(wsp + 67108864);      //   6,291,456 B
    unsigned short* Qw   = (unsigned short*)(wsp + 73400320);      //  67,108,864 B
    unsigned short* Kww  = (unsigned short*)(wsp + 140509184);     //  67,108,864 B
    unsigned short* Vw   = (unsigned short*)(wsp + 207618048);     //  67,108,864 B
    float*          part = (float*)(wsp + 274726912);              //   8,388,608 B
    unsigned short* attn = (unsigned short*)(wsp + 283115520);     //   1,048,576 B
    // total 284,164,096 bytes of ws

    k_cvt_x<<<2048, 256, 0, stream>>>(x, xb, MROWS * DHID / 8);
    k_wt<<<dim3(N3 / 32, DHID / 32), 256, 0, stream>>>(W, Wt);
    k_gemm1<<<(MROWS / 256) * (N3 / 256), 512, 0, stream>>>(xb, Wt, bias, Qw, Kww, Vw);
    k_qk<<<128 * 4, 256, 0, stream>>>(Qw, Kww, part);
    k_softmax<<<128, 64, 0, stream>>>(part, attn);
    k_out<<<128 * 16, 256, 0, stream>>>(Vw, attn, out);
}

// Round 3
// 611.945 us; speedup vs baseline: 1.0324x; 1.0324x over previous
//
#include <hip/hip_runtime.h>
#include <hip/hip_bf16.h>

// BNTChannelAttention: qkv = x@W + b; per (b,h): attn = softmax(Q^T K / 8) over
// channel dim (64x64), out = V @ attn.  B=8 N=4096 d_hid=1024 H=16 Dh=64.
//
// Round 3: fix k_gemm1's LDS swizzle. Round 2 used the 1-bit st_16x32 XOR,
// which for this frag-read shape (16 rows x 4 col-slots, 128B row stride)
// leaves 8-16 lanes/bank. Replace with 3-bit row swizzle (col_shorts ^=
// (row&7)<<3): quarter-wave lanes spread over 8 distinct 16B slots -> 2
// lanes/bank (free, m136). Staging source pre-swizzled to match (involution
// on both sides, LDS dest stays lane-linear for global_load_lds).
// All math order unchanged -> output bit-identical to rounds 1/2.

typedef __attribute__((ext_vector_type(4))) float  f32x4;
typedef __attribute__((ext_vector_type(8))) short  bf16x8;
typedef __attribute__((ext_vector_type(8))) unsigned short u16x8;

typedef __attribute__((address_space(1))) const unsigned int GBUF;
typedef __attribute__((address_space(3))) unsigned int       LBUF;

#define DEVI __device__ __forceinline__

static constexpr int BATCH = 8;
static constexpr int NSEQ  = 4096;
static constexpr int DHID  = 1024;
static constexpr int NHEAD = 16;
static constexpr int DH    = 64;
static constexpr int MROWS = BATCH * NSEQ;   // 32768
static constexpr int N3    = 3 * DHID;       // 3072

DEVI unsigned short f2bf(float f) {
    unsigned int u = __float_as_uint(f);
    u = (u + 0x7fffu + ((u >> 16) & 1u)) >> 16;   // round-to-nearest-even
    return (unsigned short)u;
}

// ---------------------------------------------------------------- 1) x -> bf16
__global__ void k_cvt_x(const float* __restrict__ x, unsigned short* __restrict__ xb, int n8) {
    int i = blockIdx.x * 256 + threadIdx.x;
    int stride = gridDim.x * 256;
    for (; i < n8; i += stride) {
        f32x4 a = *(const f32x4*)(x + (size_t)i * 8);
        f32x4 b = *(const f32x4*)(x + (size_t)i * 8 + 4);
        u16x8 r;
#pragma unroll
        for (int j = 0; j < 4; j++) { r[j] = f2bf(a[j]); r[4 + j] = f2bf(b[j]); }
        *(u16x8*)(xb + (size_t)i * 8) = r;
    }
}

// ------------------------------------------------- 2) W [1024][3072] -> Wt bf16
__global__ void k_wt(const float* __restrict__ W, unsigned short* __restrict__ Wt) {
    __shared__ float s[32][33];
    int c0 = blockIdx.x * 32;      // col in N3
    int k0 = blockIdx.y * 32;      // row in K
    int tx = threadIdx.x & 31, ty = threadIdx.x >> 5;   // 32x8
#pragma unroll
    for (int i = 0; i < 4; i++)
        s[ty + 8 * i][tx] = W[(size_t)(k0 + ty + 8 * i) * N3 + c0 + tx];
    __syncthreads();
#pragma unroll
    for (int i = 0; i < 4; i++)
        Wt[(size_t)(c0 + ty + 8 * i) * DHID + k0 + tx] = f2bf(s[tx][ty + 8 * i]);
}

// ------------------------------------------------------------- 3) QKV GEMM
// 256x256 tile, BK=64, 512 thr = 8 waves (2M x 4N), 8-phase schedule.
// LDS: As/Bs [2 buf][256 rows][64 k] bf16, swizzle col_shorts ^= (row&7)<<3.
__global__ __launch_bounds__(512, 2) void k_gemm1(
        const unsigned short* __restrict__ xb, const unsigned short* __restrict__ Wt,
        const float* __restrict__ bias,
        unsigned short* __restrict__ Q, unsigned short* __restrict__ Kw,
        unsigned short* __restrict__ V) {
    __shared__ __align__(16) unsigned short As[2][16384];
    __shared__ __align__(16) unsigned short Bs[2][16384];

    int nwg = gridDim.x;
    int cpx = nwg >> 3;                        // 1536 % 8 == 0 -> bijective
    int id  = blockIdx.x;
    int swz = (id & 7) * cpx + (id >> 3);
    int mt = swz / 12, nt = swz % 12;
    int m0 = mt * 256, n0 = nt * 256;

    int t = threadIdx.x, l = t & 63, w = t >> 6;
    int wr = w >> 2, wc = w & 3;               // 2 x 4 wave grid
    int lr = l & 15;

    const unsigned short* aSrc = xb + (size_t)m0 * DHID;
    const unsigned short* bSrc = Wt + (size_t)n0 * DHID;

    // staging: thread t covers LDS row (h*128 [+64] + t>>3), linear dest;
    // global source col pre-swizzled: col ^ ((row&7)<<3) shorts
    int scol = ((t & 7) * 8) ^ (((t >> 3) & 7) << 3);
    // frag reads: row = base + lr (base mult of 8); physical col =
    // logical(hi*8 [+32]) ^ ((l&7)<<3); second b128 at c0 ^ 32 (XOR!)
    int c0 = ((l >> 4) * 8) ^ ((l & 7) << 3);
    int aRow = wr * 128 + lr;
    int bRow = wc * 64 + lr;

#define STAGE_A(bi, kt, h) do { \
        const unsigned short* _s = aSrc + (size_t)((h) * 128 + (t >> 3)) * DHID + (kt) * 64 + scol; \
        unsigned short* _d = &As[bi][(h) * 8192 + t * 8]; \
        __builtin_amdgcn_global_load_lds((GBUF*)_s, (LBUF*)_d, 16, 0, 0); \
        __builtin_amdgcn_global_load_lds((GBUF*)(_s + 64 * DHID), (LBUF*)(_d + 4096), 16, 0, 0); \
    } while (0)
#define STAGE_B(bi, kt, h) do { \
        const unsigned short* _s = bSrc + (size_t)((h) * 128 + (t >> 3)) * DHID + (kt) * 64 + scol; \
        unsigned short* _d = &Bs[bi][(h) * 8192 + t * 8]; \
        __builtin_amdgcn_global_load_lds((GBUF*)_s, (LBUF*)_d, 16, 0, 0); \
        __builtin_amdgcn_global_load_lds((GBUF*)(_s + 64 * DHID), (LBUF*)(_d + 4096), 16, 0, 0); \
    } while (0)
#define LDA(bi, dst, mh) \
    _Pragma("unroll") for (int m2 = 0; m2 < 4; m2++) { \
        const unsigned short* _row = &As[bi][(aRow + (mh) * 64 + m2 * 16) * 64]; \
        dst[m2][0] = *(const bf16x8*)(_row + c0); \
        dst[m2][1] = *(const bf16x8*)(_row + (c0 ^ 32)); \
    }
#define LDB(bi, dst, nh) \
    _Pragma("unroll") for (int n2 = 0; n2 < 2; n2++) { \
        const unsigned short* _row = &Bs[bi][(bRow + (nh) * 32 + n2 * 16) * 64]; \
        dst[n2][0] = *(const bf16x8*)(_row + c0); \
        dst[n2][1] = *(const bf16x8*)(_row + (c0 ^ 32)); \
    }
#define MM(mh, nh, A_, B_) \
    _Pragma("unroll") for (int m2 = 0; m2 < 4; m2++) \
    _Pragma("unroll") for (int n2 = 0; n2 < 2; n2++) { \
        acc[(mh)*4+m2][(nh)*2+n2] = __builtin_amdgcn_mfma_f32_16x16x32_bf16(A_[m2][0], B_[n2][0], acc[(mh)*4+m2][(nh)*2+n2], 0, 0, 0); \
        acc[(mh)*4+m2][(nh)*2+n2] = __builtin_amdgcn_mfma_f32_16x16x32_bf16(A_[m2][1], B_[n2][1], acc[(mh)*4+m2][(nh)*2+n2], 0, 0, 0); \
    }
#define BAR __builtin_amdgcn_s_barrier()
#define LGKM0 do { asm volatile("s_waitcnt lgkmcnt(0)" ::: "memory"); \
                   __builtin_amdgcn_sched_barrier(0); } while (0)
#define VM4 asm volatile("s_waitcnt vmcnt(4)" ::: "memory")
#define PRIO1 __builtin_amdgcn_s_setprio(1)
#define PRIO0 __builtin_amdgcn_s_setprio(0)

    f32x4 acc[8][4] = {};
    bf16x8 fA0[4][2], fA1[4][2], fB0[2][2], fB1[2][2];

    // prologue: buf0 = kt0 full, buf1 = kt1 A-halves (B staged in iter0 ph0/1)
    STAGE_A(0, 0, 0); STAGE_A(0, 0, 1);
    STAGE_B(0, 0, 0); STAGE_B(0, 0, 1);
    STAGE_A(1, 1, 0); STAGE_A(1, 1, 1);
    VM4;            // oldest 8 (= all of buf0) landed
    BAR;

#pragma unroll 1
    for (int i = 0; i < 8; ++i) {
        int kc1 = 2 * i + 1;
        int kn0 = (2 * i + 2) & 15, kn1 = (2 * i + 3) & 15;  // iter7 wraps (redundant, safe)
        // ---- K-tile 2i from buf0 ----
        LDA(0, fA0, 0); LDB(0, fB0, 0); STAGE_B(1, kc1, 0);
        BAR; LGKM0; PRIO1; MM(0, 0, fA0, fB0); PRIO0; BAR;

        LDA(0, fA1, 1); STAGE_B(1, kc1, 1);
        BAR; LGKM0; PRIO1; MM(1, 0, fA1, fB0); PRIO0; BAR;

        LDB(0, fB1, 1); STAGE_A(0, kn0, 0);
        BAR; LGKM0; PRIO1; MM(1, 1, fA1, fB1); PRIO0; BAR;

        STAGE_A(0, kn0, 1);
        BAR; PRIO1; MM(0, 1, fA0, fB1); PRIO0;
        VM4;        // buf1 (A: prev ph6-7, B: ph0-1) landed
        BAR;
        // ---- K-tile 2i+1 from buf1 ----
        LDA(1, fA0, 0); LDB(1, fB0, 0); STAGE_B(0, kn0, 0);
        BAR; LGKM0; PRIO1; MM(0, 0, fA0, fB0); PRIO0; BAR;

        LDA(1, fA1, 1); STAGE_B(0, kn0, 1);
        BAR; LGKM0; PRIO1; MM(1, 0, fA1, fB0); PRIO0; BAR;

        LDB(1, fB1, 1); STAGE_A(1, kn1, 0);
        BAR; LGKM0; PRIO1; MM(1, 1, fA1, fB1); PRIO0; BAR;

        STAGE_A(1, kn1, 1);
        BAR; PRIO1; MM(0, 1, fA0, fB1); PRIO0;
        VM4;        // buf0 next content (A: ph2-3, B: ph4-5) landed
        BAR;
    }

    // epilogue: +bias, scatter to Q/K/V [b*16+h][n][e] bf16
    int hg   = nt * 4 + wc;               // head-slot 0..47 (64 cols = 1 head)
    int part = hg >> 4;
    int h    = hg & 15;
    unsigned short* dst = (part == 0) ? Q : ((part == 1) ? Kw : V);
    int b   = m0 >> 12;                   // 256-row tile never straddles batch
    int nnb = m0 & 4095;
    unsigned short* dstp = dst + ((size_t)(b * 16 + h) * NSEQ) * DH;

#pragma unroll
    for (int n = 0; n < 4; n++) {
        int e    = n * 16 + lr;
        float bv = bias[n0 + wc * 64 + n * 16 + lr];
#pragma unroll
        for (int m = 0; m < 8; m++) {
            int r0 = nnb + wr * 128 + m * 16 + (l >> 4) * 4;
#pragma unroll
            for (int j = 0; j < 4; j++)
                dstp[(size_t)(r0 + j) * DH + e] = f2bf(acc[m][n][j] + bv);
        }
    }
#undef STAGE_A
#undef STAGE_B
#undef LDA
#undef LDB
#undef MM
#undef BAR
#undef LGKM0
#undef VM4
#undef PRIO1
#undef PRIO0
}

// ------------------------------------------- 4) logit partials  P[d][e] (fp32)
// grid = 128 bh * 4 chunks; wg = 256 thr; K-chunk = 1024 rows of N.
__global__ __launch_bounds__(256, 2) void k_qk(
        const unsigned short* __restrict__ Q, const unsigned short* __restrict__ K,
        float* __restrict__ part) {
    __shared__ unsigned short Qt[64 * 40];   // [d][n] pad to 40 shorts (80B rows)
    __shared__ unsigned short Kt[64 * 40];   // 16B-aligned rows, ~2-way banks

    int bid = blockIdx.x;
    int bh = bid >> 2, ch = bid & 3;
    const unsigned short* Qb = Q + ((size_t)bh * NSEQ + ch * 1024) * DH;
    const unsigned short* Kb = K + ((size_t)bh * NSEQ + ch * 1024) * DH;

    int t = threadIdx.x, l = t & 63, w = t >> 6;
    int wr = w >> 1, wc = w & 1;
    int nn = t & 31;          // n within 32-row tile
    int dg = t >> 5;          // d-group 0..7 (8 d's each)

    f32x4 acc[2][2] = {};

    for (int ns = 0; ns < 32; ns++) {
        const size_t ro = (size_t)(ns * 32 + nn) * DH + dg * 8;
        bf16x8 qv = *(const bf16x8*)(Qb + ro);
        bf16x8 kv = *(const bf16x8*)(Kb + ro);
        __syncthreads();                       // prior frag reads done
#pragma unroll
        for (int j = 0; j < 8; j++) {
            Qt[(dg * 8 + j) * 40 + nn] = qv[j];
            Kt[(dg * 8 + j) * 40 + nn] = kv[j];
        }
        __syncthreads();
        bf16x8 a[2], b[2];
#pragma unroll
        for (int m = 0; m < 2; m++)
            a[m] = *(const bf16x8*)(Qt + (wr * 32 + m * 16 + (l & 15)) * 40 + (l >> 4) * 8);
#pragma unroll
        for (int n = 0; n < 2; n++)
            b[n] = *(const bf16x8*)(Kt + (wc * 32 + n * 16 + (l & 15)) * 40 + (l >> 4) * 8);
#pragma unroll
        for (int m = 0; m < 2; m++)
#pragma unroll
            for (int n = 0; n < 2; n++)
                acc[m][n] = __builtin_amdgcn_mfma_f32_16x16x32_bf16(a[m], b[n], acc[m][n], 0, 0, 0);
    }

    float* P = part + ((size_t)ch * 128 + bh) * 4096;
#pragma unroll
    for (int m = 0; m < 2; m++)
#pragma unroll
        for (int n = 0; n < 2; n++)
#pragma unroll
            for (int j = 0; j < 4; j++) {
                int d = wr * 32 + m * 16 + (l >> 4) * 4 + j;
                int e = wc * 32 + n * 16 + (l & 15);
                P[d * 64 + e] = acc[m][n][j];
            }
}

// --------------------------------------- 5) softmax over e, write attn^T bf16
__global__ void k_softmax(const float* __restrict__ part, unsigned short* __restrict__ attn_t) {
    int bh = blockIdx.x;          // 128
    int d  = threadIdx.x;         // 64
    const float* p = part + (size_t)bh * 4096 + d * 64;
    const size_t cs = (size_t)128 * 4096;
    float s[64];
#pragma unroll
    for (int e = 0; e < 64; e++)
        s[e] = (p[e] + p[cs + e] + p[2 * cs + e] + p[3 * cs + e]) * 0.125f;
    float mx = s[0];
#pragma unroll
    for (int e = 1; e < 64; e++) mx = fmaxf(mx, s[e]);
    float sum = 0.f;
#pragma unroll
    for (int e = 0; e < 64; e++) { s[e] = __expf(s[e] - mx); sum += s[e]; }
    float inv = 1.f / sum;
    unsigned short* a = attn_t + (size_t)bh * 4096;
#pragma unroll
    for (int e = 0; e < 64; e++)
        a[e * 64 + d] = f2bf(s[e] * inv);     // [e][d] layout for PV B-frags
}

// ------------------------------------------------------- 6) out = V @ attn
// grid = 128 bh * 16 row-tiles; wave owns 64 rows x 64 cols; no LDS.
__global__ __launch_bounds__(256, 2) void k_out(
        const unsigned short* __restrict__ V, const unsigned short* __restrict__ attn_t,
        float* __restrict__ out) {
    int bid = blockIdx.x;
    int bh = bid >> 4, ntile = bid & 15;
    int b = bh >> 4, h = bh & 15;
    int t = threadIdx.x, l = t & 63, w = t >> 6;
    int r0 = ntile * 256 + w * 64;

    const unsigned short* Vb = V + (size_t)bh * NSEQ * DH;
    const unsigned short* Ab = attn_t + (size_t)bh * 4096;

    bf16x8 bf[4][2];
#pragma unroll
    for (int n = 0; n < 4; n++)
#pragma unroll
        for (int ks = 0; ks < 2; ks++)
            bf[n][ks] = *(const bf16x8*)(Ab + (n * 16 + (l & 15)) * 64 + ks * 32 + (l >> 4) * 8);

    f32x4 acc[4][4] = {};
#pragma unroll
    for (int m = 0; m < 4; m++) {
        const unsigned short* vr = Vb + (size_t)(r0 + m * 16 + (l & 15)) * DH + (l >> 4) * 8;
        bf16x8 av0 = *(const bf16x8*)(vr);
        bf16x8 av1 = *(const bf16x8*)(vr + 32);
#pragma unroll
        for (int n = 0; n < 4; n++) {
            acc[m][n] = __builtin_amdgcn_mfma_f32_16x16x32_bf16(av0, bf[n][0], acc[m][n], 0, 0, 0);
            acc[m][n] = __builtin_amdgcn_mfma_f32_16x16x32_bf16(av1, bf[n][1], acc[m][n], 0, 0, 0);
        }
    }

    float* ob = out + (size_t)b * NSEQ * DHID + (size_t)h * DH;
#pragma unroll
    for (int m = 0; m < 4; m++)
#pragma unroll
        for (int n = 0; n < 4; n++)
#pragma unroll
            for (int j = 0; j < 4; j++) {
                int nn = r0 + m * 16 + (l >> 4) * 4 + j;
                int e  = n * 16 + (l & 15);
                ob[(size_t)nn * DHID + e] = acc[m][n][j];
            }
}

// ---------------------------------------------------------------- launcher
extern "C" void kernel_launch(void* const* d_in, const int* in_sizes, int n_in,
                              void* d_out, int out_size, void* d_ws, size_t ws_size,
                              hipStream_t stream) {
    const float* x    = (const float*)d_in[0];
    const float* W    = (const float*)d_in[1];
    const float* bias = (const float*)d_in[2];
    float* out = (float*)d_out;

    char* wsp = (char*)d_ws;
    unsigned short* xb   = (unsigned short*)(wsp);                 //  67,108,864 B
    unsigned short* Wt   = (unsigned short*)(wsp + 67108864);      //   6,291,456 B
    unsigned short* Qw   = (unsigned short*)(wsp + 73400320);      //  67,108,864 B
    unsigned short* Kww  = (unsigned short*)(wsp + 140509184);     //  67,108,864 B
    unsigned short* Vw   = (unsigned short*)(wsp + 207618048);     //  67,108,864 B
    float*          part = (float*)(wsp + 274726912);              //   8,388,608 B
    unsigned short* attn = (unsigned short*)(wsp + 283115520);     //   1,048,576 B
    // total 284,164,096 bytes of ws

    k_cvt_x<<<2048, 256, 0, stream>>>(x, xb, MROWS * DHID / 8);
    k_wt<<<dim3(N3 / 32, DHID / 32), 256, 0, stream>>>(W, Wt);
    k_gemm1<<<(MROWS / 256) * (N3 / 256), 512, 0, stream>>>(xb, Wt, bias, Qw, Kww, Vw);
    k_qk<<<128 * 4, 256, 0, stream>>>(Qw, Kww, part);
    k_softmax<<<128, 64, 0, stream>>>(part, attn);
    k_out<<<128 * 16, 256, 0, stream>>>(Vw, attn, out);
}

// Round 5
// 547.404 us; speedup vs baseline: 1.1541x; 1.1179x over previous
//
#include <hip/hip_runtime.h>
#include <hip/hip_bf16.h>

// BNTChannelAttention: qkv = x@W + b; per (b,h): attn = softmax(Q^T K / 8) over
// channel dim (64x64), out = V @ attn.  B=8 N=4096 d_hid=1024 H=16 Dh=64.
//
// Round 5 = round 4 resubmitted (GPU acquisition timeout, never measured):
//  (A) k_gemm1 epilogue: replace 2B-scattered QKV stores (write-allocate RMW,
//      ~130MB extra FETCH) with per-wave LDS transpose (16KB slice, XOR-swizzled
//      conflict-free) + 16B/lane coalesced stores.
//  (B) k_qk: register-prefetch next iteration's Q/K rows to overlap global
//      latency with MFMA (was serial: load -> barrier -> use, 32x).
// Output bit-identical to rounds 1-3 (absmax 0.2119141).

typedef __attribute__((ext_vector_type(4))) float  f32x4;
typedef __attribute__((ext_vector_type(8))) short  bf16x8;
typedef __attribute__((ext_vector_type(8))) unsigned short u16x8;

typedef __attribute__((address_space(1))) const unsigned int GBUF;
typedef __attribute__((address_space(3))) unsigned int       LBUF;

#define DEVI __device__ __forceinline__

static constexpr int BATCH = 8;
static constexpr int NSEQ  = 4096;
static constexpr int DHID  = 1024;
static constexpr int NHEAD = 16;
static constexpr int DH    = 64;
static constexpr int MROWS = BATCH * NSEQ;   // 32768
static constexpr int N3    = 3 * DHID;       // 3072

DEVI unsigned short f2bf(float f) {
    unsigned int u = __float_as_uint(f);
    u = (u + 0x7fffu + ((u >> 16) & 1u)) >> 16;   // round-to-nearest-even
    return (unsigned short)u;
}

// ---------------------------------------------------------------- 1) x -> bf16
__global__ void k_cvt_x(const float* __restrict__ x, unsigned short* __restrict__ xb, int n8) {
    int i = blockIdx.x * 256 + threadIdx.x;
    int stride = gridDim.x * 256;
    for (; i < n8; i += stride) {
        f32x4 a = *(const f32x4*)(x + (size_t)i * 8);
        f32x4 b = *(const f32x4*)(x + (size_t)i * 8 + 4);
        u16x8 r;
#pragma unroll
        for (int j = 0; j < 4; j++) { r[j] = f2bf(a[j]); r[4 + j] = f2bf(b[j]); }
        *(u16x8*)(xb + (size_t)i * 8) = r;
    }
}

// ------------------------------------------------- 2) W [1024][3072] -> Wt bf16
__global__ void k_wt(const float* __restrict__ W, unsigned short* __restrict__ Wt) {
    __shared__ float s[32][33];
    int c0 = blockIdx.x * 32;      // col in N3
    int k0 = blockIdx.y * 32;      // row in K
    int tx = threadIdx.x & 31, ty = threadIdx.x >> 5;   // 32x8
#pragma unroll
    for (int i = 0; i < 4; i++)
        s[ty + 8 * i][tx] = W[(size_t)(k0 + ty + 8 * i) * N3 + c0 + tx];
    __syncthreads();
#pragma unroll
    for (int i = 0; i < 4; i++)
        Wt[(size_t)(c0 + ty + 8 * i) * DHID + k0 + tx] = f2bf(s[tx][ty + 8 * i]);
}

// ------------------------------------------------------------- 3) QKV GEMM
// 256x256 tile, BK=64, 512 thr = 8 waves (2M x 4N), 8-phase schedule.
// LDS: As/Bs [2 buf][256 rows][64 k] bf16, swizzle col_shorts ^= (row&7)<<3.
__global__ __launch_bounds__(512, 2) void k_gemm1(
        const unsigned short* __restrict__ xb, const unsigned short* __restrict__ Wt,
        const float* __restrict__ bias,
        unsigned short* __restrict__ Q, unsigned short* __restrict__ Kw,
        unsigned short* __restrict__ V) {
    __shared__ __align__(16) unsigned short As[2][16384];
    __shared__ __align__(16) unsigned short Bs[2][16384];

    int nwg = gridDim.x;
    int cpx = nwg >> 3;                        // 1536 % 8 == 0 -> bijective
    int id  = blockIdx.x;
    int swz = (id & 7) * cpx + (id >> 3);
    int mt = swz / 12, nt = swz % 12;
    int m0 = mt * 256, n0 = nt * 256;

    int t = threadIdx.x, l = t & 63, w = t >> 6;
    int wr = w >> 2, wc = w & 3;               // 2 x 4 wave grid
    int lr = l & 15;

    const unsigned short* aSrc = xb + (size_t)m0 * DHID;
    const unsigned short* bSrc = Wt + (size_t)n0 * DHID;

    // staging: thread t covers LDS row (h*128 [+64] + t>>3), linear dest;
    // global source col pre-swizzled: col ^ ((row&7)<<3) shorts
    int scol = ((t & 7) * 8) ^ (((t >> 3) & 7) << 3);
    // frag reads: physical col = logical ^ ((row&7)<<3); second b128 at c0^32
    int c0 = ((l >> 4) * 8) ^ ((l & 7) << 3);
    int aRow = wr * 128 + lr;
    int bRow = wc * 64 + lr;

#define STAGE_A(bi, kt, h) do { \
        const unsigned short* _s = aSrc + (size_t)((h) * 128 + (t >> 3)) * DHID + (kt) * 64 + scol; \
        unsigned short* _d = &As[bi][(h) * 8192 + t * 8]; \
        __builtin_amdgcn_global_load_lds((GBUF*)_s, (LBUF*)_d, 16, 0, 0); \
        __builtin_amdgcn_global_load_lds((GBUF*)(_s + 64 * DHID), (LBUF*)(_d + 4096), 16, 0, 0); \
    } while (0)
#define STAGE_B(bi, kt, h) do { \
        const unsigned short* _s = bSrc + (size_t)((h) * 128 + (t >> 3)) * DHID + (kt) * 64 + scol; \
        unsigned short* _d = &Bs[bi][(h) * 8192 + t * 8]; \
        __builtin_amdgcn_global_load_lds((GBUF*)_s, (LBUF*)_d, 16, 0, 0); \
        __builtin_amdgcn_global_load_lds((GBUF*)(_s + 64 * DHID), (LBUF*)(_d + 4096), 16, 0, 0); \
    } while (0)
#define LDA(bi, dst, mh) \
    _Pragma("unroll") for (int m2 = 0; m2 < 4; m2++) { \
        const unsigned short* _row = &As[bi][(aRow + (mh) * 64 + m2 * 16) * 64]; \
        dst[m2][0] = *(const bf16x8*)(_row + c0); \
        dst[m2][1] = *(const bf16x8*)(_row + (c0 ^ 32)); \
    }
#define LDB(bi, dst, nh) \
    _Pragma("unroll") for (int n2 = 0; n2 < 2; n2++) { \
        const unsigned short* _row = &Bs[bi][(bRow + (nh) * 32 + n2 * 16) * 64]; \
        dst[n2][0] = *(const bf16x8*)(_row + c0); \
        dst[n2][1] = *(const bf16x8*)(_row + (c0 ^ 32)); \
    }
#define MM(mh, nh, A_, B_) \
    _Pragma("unroll") for (int m2 = 0; m2 < 4; m2++) \
    _Pragma("unroll") for (int n2 = 0; n2 < 2; n2++) { \
        acc[(mh)*4+m2][(nh)*2+n2] = __builtin_amdgcn_mfma_f32_16x16x32_bf16(A_[m2][0], B_[n2][0], acc[(mh)*4+m2][(nh)*2+n2], 0, 0, 0); \
        acc[(mh)*4+m2][(nh)*2+n2] = __builtin_amdgcn_mfma_f32_16x16x32_bf16(A_[m2][1], B_[n2][1], acc[(mh)*4+m2][(nh)*2+n2], 0, 0, 0); \
    }
#define BAR __builtin_amdgcn_s_barrier()
#define LGKM0 do { asm volatile("s_waitcnt lgkmcnt(0)" ::: "memory"); \
                   __builtin_amdgcn_sched_barrier(0); } while (0)
#define VM4 asm volatile("s_waitcnt vmcnt(4)" ::: "memory")
#define VM0 asm volatile("s_waitcnt vmcnt(0)" ::: "memory")
#define PRIO1 __builtin_amdgcn_s_setprio(1)
#define PRIO0 __builtin_amdgcn_s_setprio(0)

    f32x4 acc[8][4] = {};
    bf16x8 fA0[4][2], fA1[4][2], fB0[2][2], fB1[2][2];

    // prologue: buf0 = kt0 full, buf1 = kt1 A-halves (B staged in iter0 ph0/1)
    STAGE_A(0, 0, 0); STAGE_A(0, 0, 1);
    STAGE_B(0, 0, 0); STAGE_B(0, 0, 1);
    STAGE_A(1, 1, 0); STAGE_A(1, 1, 1);
    VM4;            // oldest 8 (= all of buf0) landed
    BAR;

#pragma unroll 1
    for (int i = 0; i < 8; ++i) {
        int kc1 = 2 * i + 1;
        int kn0 = (2 * i + 2) & 15, kn1 = (2 * i + 3) & 15;  // iter7 wraps (redundant, safe)
        // ---- K-tile 2i from buf0 ----
        LDA(0, fA0, 0); LDB(0, fB0, 0); STAGE_B(1, kc1, 0);
        BAR; LGKM0; PRIO1; MM(0, 0, fA0, fB0); PRIO0; BAR;

        LDA(0, fA1, 1); STAGE_B(1, kc1, 1);
        BAR; LGKM0; PRIO1; MM(1, 0, fA1, fB0); PRIO0; BAR;

        LDB(0, fB1, 1); STAGE_A(0, kn0, 0);
        BAR; LGKM0; PRIO1; MM(1, 1, fA1, fB1); PRIO0; BAR;

        STAGE_A(0, kn0, 1);
        BAR; PRIO1; MM(0, 1, fA0, fB1); PRIO0;
        VM4;        // buf1 (A: prev ph6-7, B: ph0-1) landed
        BAR;
        // ---- K-tile 2i+1 from buf1 ----
        LDA(1, fA0, 0); LDB(1, fB0, 0); STAGE_B(0, kn0, 0);
        BAR; LGKM0; PRIO1; MM(0, 0, fA0, fB0); PRIO0; BAR;

        LDA(1, fA1, 1); STAGE_B(0, kn0, 1);
        BAR; LGKM0; PRIO1; MM(1, 0, fA1, fB0); PRIO0; BAR;

        LDB(1, fB1, 1); STAGE_A(1, kn1, 0);
        BAR; LGKM0; PRIO1; MM(1, 1, fA1, fB1); PRIO0; BAR;

        STAGE_A(1, kn1, 1);
        BAR; PRIO1; MM(0, 1, fA0, fB1); PRIO0;
        VM4;        // buf0 next content (A: ph2-3, B: ph4-5) landed
        BAR;
    }

    // ---- epilogue: +bias, LDS-transpose, coalesced 16B stores ----
    // drain all in-flight global_load_lds (they write As/Bs), then barrier.
    VM0;
    BAR;

    int hg   = nt * 4 + wc;               // head-slot 0..47 (64 cols = 1 head)
    int part = hg >> 4;
    int h    = hg & 15;
    unsigned short* dst = (part == 0) ? Q : ((part == 1) ? Kw : V);
    int b   = m0 >> 12;                   // 256-row tile never straddles batch
    int nnb = m0 & 4095;
    unsigned short* dstp = dst + ((size_t)(b * 16 + h) * NSEQ) * DH;

    // per-wave private 16KB LDS slice (no cross-wave sharing -> no barriers)
    unsigned short* eb = (w < 4) ? (&As[0][0] + w * 8192) : (&Bs[0][0] + (w - 4) * 8192);

    float bv[4];
#pragma unroll
    for (int n = 0; n < 4; n++) bv[n] = bias[n0 + wc * 64 + n * 16 + lr];

    // write: value at (local row lm, col e) -> eb[lm*64 + (e ^ ((lm>>2 & 3)<<4))]
    // banks: ((n^hi)&3)*8 + lr/2 -> 32 banks x 2 lanes = conflict-free
#pragma unroll
    for (int n = 0; n < 4; n++)
#pragma unroll
        for (int m = 0; m < 8; m++)
#pragma unroll
            for (int j = 0; j < 4; j++) {
                int lm = m * 16 + (l >> 4) * 4 + j;
                eb[lm * 64 + ((n * 16 + lr) ^ (((lm >> 2) & 3) << 4))] =
                    f2bf(acc[m][n][j] + bv[n]);
            }

    // read back 16B/lane (order-preserving inverse swizzle) + coalesced store
    const size_t base2 = (size_t)(nnb + wr * 128) * DH;
#pragma unroll
    for (int rr = 0; rr < 16; rr++) {
        int u = rr * 64 + l;              // flat 16B-unit index 0..1023
        int row = u >> 3, unit = u & 7;
        bf16x8 v = *(const bf16x8*)&eb[row * 64 + ((unit * 8) ^ (((row >> 2) & 3) << 4))];
        *(bf16x8*)(dstp + base2 + (size_t)u * 8) = v;
    }
#undef STAGE_A
#undef STAGE_B
#undef LDA
#undef LDB
#undef MM
#undef BAR
#undef LGKM0
#undef VM4
#undef VM0
#undef PRIO1
#undef PRIO0
}

// ------------------------------------------- 4) logit partials  P[d][e] (fp32)
// grid = 128 bh * 4 chunks; wg = 256 thr; K-chunk = 1024 rows of N.
// Register-prefetch pipeline: iter ns+1's global loads issue before iter ns's
// barriers/MFMA, hiding ~900cy HBM latency under compute.
__global__ __launch_bounds__(256, 2) void k_qk(
        const unsigned short* __restrict__ Q, const unsigned short* __restrict__ K,
        float* __restrict__ part) {
    __shared__ unsigned short Qt[64 * 40];   // [d][n] pad to 40 shorts (80B rows)
    __shared__ unsigned short Kt[64 * 40];

    int bid = blockIdx.x;
    int bh = bid >> 2, ch = bid & 3;
    const unsigned short* Qb = Q + ((size_t)bh * NSEQ + ch * 1024) * DH;
    const unsigned short* Kb = K + ((size_t)bh * NSEQ + ch * 1024) * DH;

    int t = threadIdx.x, l = t & 63, w = t >> 6;
    int wr = w >> 1, wc = w & 1;
    int nn = t & 31;          // n within 32-row tile
    int dg = t >> 5;          // d-group 0..7 (8 d's each)

    f32x4 acc[2][2] = {};

    size_t ro0 = (size_t)nn * DH + dg * 8;
    bf16x8 qv = *(const bf16x8*)(Qb + ro0);
    bf16x8 kv = *(const bf16x8*)(Kb + ro0);

    for (int ns = 0; ns < 32; ns++) {
        // prefetch next iteration (wraps on last iter; harmless in-bounds load)
        const size_t rn = (size_t)((((ns + 1) & 31) * 32) + nn) * DH + dg * 8;
        bf16x8 qn = *(const bf16x8*)(Qb + rn);
        bf16x8 kn = *(const bf16x8*)(Kb + rn);
        __syncthreads();                       // prior frag reads done
#pragma unroll
        for (int j = 0; j < 8; j++) {
            Qt[(dg * 8 + j) * 40 + nn] = qv[j];
            Kt[(dg * 8 + j) * 40 + nn] = kv[j];
        }
        __syncthreads();
        bf16x8 a[2], b[2];
#pragma unroll
        for (int m = 0; m < 2; m++)
            a[m] = *(const bf16x8*)(Qt + (wr * 32 + m * 16 + (l & 15)) * 40 + (l >> 4) * 8);
#pragma unroll
        for (int n = 0; n < 2; n++)
            b[n] = *(const bf16x8*)(Kt + (wc * 32 + n * 16 + (l & 15)) * 40 + (l >> 4) * 8);
#pragma unroll
        for (int m = 0; m < 2; m++)
#pragma unroll
            for (int n = 0; n < 2; n++)
                acc[m][n] = __builtin_amdgcn_mfma_f32_16x16x32_bf16(a[m], b[n], acc[m][n], 0, 0, 0);
        qv = qn; kv = kn;
    }

    float* P = part + ((size_t)ch * 128 + bh) * 4096;
#pragma unroll
    for (int m = 0; m < 2; m++)
#pragma unroll
        for (int n = 0; n < 2; n++)
#pragma unroll
            for (int j = 0; j < 4; j++) {
                int d = wr * 32 + m * 16 + (l >> 4) * 4 + j;
                int e = wc * 32 + n * 16 + (l & 15);
                P[d * 64 + e] = acc[m][n][j];
            }
}

// --------------------------------------- 5) softmax over e, write attn^T bf16
__global__ void k_softmax(const float* __restrict__ part, unsigned short* __restrict__ attn_t) {
    int bh = blockIdx.x;          // 128
    int d  = threadIdx.x;         // 64
    const float* p = part + (size_t)bh * 4096 + d * 64;
    const size_t cs = (size_t)128 * 4096;
    float s[64];
#pragma unroll
    for (int e = 0; e < 64; e++)
        s[e] = (p[e] + p[cs + e] + p[2 * cs + e] + p[3 * cs + e]) * 0.125f;
    float mx = s[0];
#pragma unroll
    for (int e = 1; e < 64; e++) mx = fmaxf(mx, s[e]);
    float sum = 0.f;
#pragma unroll
    for (int e = 0; e < 64; e++) { s[e] = __expf(s[e] - mx); sum += s[e]; }
    float inv = 1.f / sum;
    unsigned short* a = attn_t + (size_t)bh * 4096;
#pragma unroll
    for (int e = 0; e < 64; e++)
        a[e * 64 + d] = f2bf(s[e] * inv);     // [e][d] layout for PV B-frags
}

// ------------------------------------------------------- 6) out = V @ attn
// grid = 128 bh * 16 row-tiles; wave owns 64 rows x 64 cols; no LDS.
__global__ __launch_bounds__(256, 2) void k_out(
        const unsigned short* __restrict__ V, const unsigned short* __restrict__ attn_t,
        float* __restrict__ out) {
    int bid = blockIdx.x;
    int bh = bid >> 4, ntile = bid & 15;
    int b = bh >> 4, h = bh & 15;
    int t = threadIdx.x, l = t & 63, w = t >> 6;
    int r0 = ntile * 256 + w * 64;

    const unsigned short* Vb = V + (size_t)bh * NSEQ * DH;
    const unsigned short* Ab = attn_t + (size_t)bh * 4096;

    bf16x8 bf[4][2];
#pragma unroll
    for (int n = 0; n < 4; n++)
#pragma unroll
        for (int ks = 0; ks < 2; ks++)
            bf[n][ks] = *(const bf16x8*)(Ab + (n * 16 + (l & 15)) * 64 + ks * 32 + (l >> 4) * 8);

    f32x4 acc[4][4] = {};
#pragma unroll
    for (int m = 0; m < 4; m++) {
        const unsigned short* vr = Vb + (size_t)(r0 + m * 16 + (l & 15)) * DH + (l >> 4) * 8;
        bf16x8 av0 = *(const bf16x8*)(vr);
        bf16x8 av1 = *(const bf16x8*)(vr + 32);
#pragma unroll
        for (int n = 0; n < 4; n++) {
            acc[m][n] = __builtin_amdgcn_mfma_f32_16x16x32_bf16(av0, bf[n][0], acc[m][n], 0, 0, 0);
            acc[m][n] = __builtin_amdgcn_mfma_f32_16x16x32_bf16(av1, bf[n][1], acc[m][n], 0, 0, 0);
        }
    }

    float* ob = out + (size_t)b * NSEQ * DHID + (size_t)h * DH;
#pragma unroll
    for (int m = 0; m < 4; m++)
#pragma unroll
        for (int n = 0; n < 4; n++)
#pragma unroll
            for (int j = 0; j < 4; j++) {
                int nn = r0 + m * 16 + (l >> 4) * 4 + j;
                int e  = n * 16 + (l & 15);
                ob[(size_t)nn * DHID + e] = acc[m][n][j];
            }
}

// ---------------------------------------------------------------- launcher
extern "C" void kernel_launch(void* const* d_in, const int* in_sizes, int n_in,
                              void* d_out, int out_size, void* d_ws, size_t ws_size,
                              hipStream_t stream) {
    const float* x    = (const float*)d_in[0];
    const float* W    = (const float*)d_in[1];
    const float* bias = (const float*)d_in[2];
    float* out = (float*)d_out;

    char* wsp = (char*)d_ws;
    unsigned short* xb   = (unsigned short*)(wsp);                 //  67,108,864 B
    unsigned short* Wt   = (unsigned short*)(wsp + 67108864);      //   6,291,456 B
    unsigned short* Qw   = (unsigned short*)(wsp + 73400320);      //  67,108,864 B
    unsigned short* Kww  = (unsigned short*)(wsp + 140509184);     //  67,108,864 B
    unsigned short* Vw   = (unsigned short*)(wsp + 207618048);     //  67,108,864 B
    float*          part = (float*)(wsp + 274726912);              //   8,388,608 B
    unsigned short* attn = (unsigned short*)(wsp + 283115520);     //   1,048,576 B
    // total 284,164,096 bytes of ws

    k_cvt_x<<<2048, 256, 0, stream>>>(x, xb, MROWS * DHID / 8);
    k_wt<<<dim3(N3 / 32, DHID / 32), 256, 0, stream>>>(W, Wt);
    k_gemm1<<<(MROWS / 256) * (N3 / 256), 512, 0, stream>>>(xb, Wt, bias, Qw, Kww, Vw);
    k_qk<<<128 * 4, 256, 0, stream>>>(Qw, Kww, part);
    k_softmax<<<128, 64, 0, stream>>>(part, attn);
    k_out<<<128 * 16, 256, 0, stream>>>(Vw, attn, out);
}